// Round 1
// baseline (4526.494 us; speedup 1.0000x reference)
//
#include <hip/hip_runtime.h>
#include <hip/hip_bf16.h>

#define DIM 64
#define NRELS 8
#define NBASES 4
#define KROWS 576  // 64 self + 8*64 relation rows

// Build Wcat [576][64]: rows 0..63 = wself[i][j]; rows 64+r*64+i = sum_b coef[r][b]*bases[b][i][j]
__global__ void build_wcat(const float* __restrict__ bases, const float* __restrict__ coef,
                           const float* __restrict__ wself, float* __restrict__ Wcat) {
    int idx = blockIdx.x * blockDim.x + threadIdx.x;
    if (idx >= KROWS * DIM) return;
    int row = idx >> 6, j = idx & 63;
    float v;
    if (row < DIM) {
        v = wself[row * DIM + j];
    } else {
        int r = (row - DIM) >> 6, i = (row - DIM) & 63;
        v = 0.f;
#pragma unroll
        for (int b = 0; b < NBASES; ++b)
            v += coef[r * NBASES + b] * bases[((size_t)b * DIM + i) * DIM + j];
    }
    Wcat[idx] = v;
}

// Scatter: S[dst][etype][:] += h[src][:]   (dense path)
__global__ void scatter_kernel(const int* __restrict__ src, const int* __restrict__ dst,
                               const int* __restrict__ et, const float* __restrict__ h,
                               float* __restrict__ S, int n_edges) {
    int gid = blockIdx.x * blockDim.x + threadIdx.x;
    int wave = gid >> 6, lane = gid & 63;
    int nw = (gridDim.x * blockDim.x) >> 6;
    for (int e = wave; e < n_edges; e += nw) {
        int s = src[e], d = dst[e], r = et[e];
        float v = h[(size_t)s * DIM + lane];
        unsafeAtomicAdd(&S[((size_t)d * NRELS + r) * DIM + lane], v);
    }
}

// Fused matmul: out[n][j] = bias[j] + sum_k x[n][k]*Wcat[k][j]
// x[n] = concat(h[n][0:64], S[n][0:512]) when USE_S, else just h.
template <bool USE_S>
__global__ void rgcn_matmul(const float* __restrict__ h, const float* __restrict__ S,
                            const float* __restrict__ Wcat, const float* __restrict__ bias,
                            float* __restrict__ out, int n_nodes) {
    const int R = 8;  // rows per wave
    int gid = blockIdx.x * blockDim.x + threadIdx.x;
    int wave = gid >> 6, lane = gid & 63;
    int nw = (gridDim.x * blockDim.x) >> 6;
    int ngroups = n_nodes / R;  // 100000 % 8 == 0
    float bv = bias[lane];
    const int KB = USE_S ? 9 : 1;  // 64-wide k-blocks
    for (int g = wave; g < ngroups; g += nw) {
        int n0 = g * R;
        float xr[8][9];
#pragma unroll
        for (int rr = 0; rr < R; ++rr) {
            size_t n = (size_t)(n0 + rr);
            xr[rr][0] = h[n * DIM + lane];
            if (USE_S) {
#pragma unroll
                for (int k = 0; k < NRELS; ++k)
                    xr[rr][1 + k] = S[n * (NRELS * DIM) + k * DIM + lane];
            }
        }
        float acc[8];
#pragma unroll
        for (int rr = 0; rr < R; ++rr) acc[rr] = bv;
#pragma unroll
        for (int k = 0; k < 9; ++k) {
            if (k >= KB) break;
#pragma unroll
            for (int l = 0; l < 64; ++l) {
                float w = Wcat[(k * 64 + l) * DIM + lane];
#pragma unroll
                for (int rr = 0; rr < R; ++rr) {
                    float xv = __shfl(xr[rr][k], l);
                    acc[rr] += xv * w;
                }
            }
        }
#pragma unroll
        for (int rr = 0; rr < R; ++rr)
            out[(size_t)(n0 + rr) * DIM + lane] = acc[rr];
    }
}

// Fallback (small ws): per-edge matvec, atomics into out
__global__ void edge_matvec(const int* __restrict__ src, const int* __restrict__ dst,
                            const int* __restrict__ et, const float* __restrict__ h,
                            const float* __restrict__ Wcat, float* __restrict__ out,
                            int n_edges) {
    int gid = blockIdx.x * blockDim.x + threadIdx.x;
    int wave = gid >> 6, lane = gid & 63;
    int nw = (gridDim.x * blockDim.x) >> 6;
    for (int e = wave; e < n_edges; e += nw) {
        int s = src[e], d = dst[e], r = et[e];
        float hreg = h[(size_t)s * DIM + lane];
        float acc = 0.f;
#pragma unroll
        for (int l = 0; l < 64; ++l) {
            float xv = __shfl(hreg, l);
            acc += xv * Wcat[(DIM + r * DIM + l) * DIM + lane];
        }
        unsafeAtomicAdd(&out[(size_t)d * DIM + lane], acc);
    }
}

extern "C" void kernel_launch(void* const* d_in, const int* in_sizes, int n_in,
                              void* d_out, int out_size, void* d_ws, size_t ws_size,
                              hipStream_t stream) {
    const int* src = (const int*)d_in[0];
    const int* dst = (const int*)d_in[1];
    const int* et  = (const int*)d_in[2];
    const float* emb    = (const float*)d_in[3];
    const float* bases1 = (const float*)d_in[4];
    const float* coef1  = (const float*)d_in[5];
    const float* wself1 = (const float*)d_in[6];
    const float* bias1  = (const float*)d_in[7];
    const float* bases2 = (const float*)d_in[8];
    const float* coef2  = (const float*)d_in[9];
    const float* wself2 = (const float*)d_in[10];
    const float* bias2  = (const float*)d_in[11];
    float* out = (float*)d_out;

    const int NE = in_sizes[0];
    const int NN = in_sizes[3] / DIM;

    float* Wcat1 = (float*)d_ws;
    float* Wcat2 = Wcat1 + KROWS * DIM;
    float* h1    = Wcat2 + KROWS * DIM;
    float* S     = h1 + (size_t)NN * DIM;

    size_t need_dense = ((size_t)2 * KROWS * DIM + (size_t)NN * DIM + (size_t)NN * NRELS * DIM) * 4;

    build_wcat<<<(KROWS * DIM + 255) / 256, 256, 0, stream>>>(bases1, coef1, wself1, Wcat1);
    build_wcat<<<(KROWS * DIM + 255) / 256, 256, 0, stream>>>(bases2, coef2, wself2, Wcat2);

    if (ws_size >= need_dense) {
        size_t sbytes = (size_t)NN * NRELS * DIM * 4;
        hipMemsetAsync(S, 0, sbytes, stream);
        scatter_kernel<<<2048, 256, 0, stream>>>(src, dst, et, emb, S, NE);
        rgcn_matmul<true><<<2048, 256, 0, stream>>>(emb, S, Wcat1, bias1, h1, NN);
        hipMemsetAsync(S, 0, sbytes, stream);
        scatter_kernel<<<2048, 256, 0, stream>>>(src, dst, et, h1, S, NE);
        rgcn_matmul<true><<<2048, 256, 0, stream>>>(h1, S, Wcat2, bias2, out, NN);
    } else {
        // Fallback: needs only ~26 MB ws
        rgcn_matmul<false><<<2048, 256, 0, stream>>>(emb, nullptr, Wcat1, bias1, h1, NN);
        edge_matvec<<<2048, 256, 0, stream>>>(src, dst, et, emb, Wcat1, h1, NE);
        rgcn_matmul<false><<<2048, 256, 0, stream>>>(h1, nullptr, Wcat2, bias2, out, NN);
        edge_matvec<<<2048, 256, 0, stream>>>(src, dst, et, h1, Wcat2, out, NE);
    }
}

// Round 2
// 2510.064 us; speedup vs baseline: 1.8033x; 1.8033x over previous
//
#include <hip/hip_runtime.h>
#include <hip/hip_bf16.h>

#define DIM 64
#define NRELS 8
#define NBASES 4
#define KROWS 576  // 64 self + 8*64 relation rows

// Build Wcat [576][64]: rows 0..63 = wself; rows 64+r*64+i = sum_b coef[r][b]*bases[b][i][j]
__global__ void build_wcat(const float* __restrict__ bases, const float* __restrict__ coef,
                           const float* __restrict__ wself, float* __restrict__ Wcat) {
    int idx = blockIdx.x * blockDim.x + threadIdx.x;
    if (idx >= KROWS * DIM) return;
    int row = idx >> 6, j = idx & 63;
    float v;
    if (row < DIM) {
        v = wself[row * DIM + j];
    } else {
        int r = (row - DIM) >> 6, i = (row - DIM) & 63;
        v = 0.f;
#pragma unroll
        for (int b = 0; b < NBASES; ++b)
            v += coef[r * NBASES + b] * bases[((size_t)b * DIM + i) * DIM + j];
    }
    Wcat[idx] = v;
}

// Scatter: S[dst][etype][:] += h[src][:]
__global__ void scatter_kernel(const int* __restrict__ src, const int* __restrict__ dst,
                               const int* __restrict__ et, const float* __restrict__ h,
                               float* __restrict__ S, int n_edges) {
    int gid = blockIdx.x * blockDim.x + threadIdx.x;
    int wave = gid >> 6, lane = gid & 63;
    int nw = (gridDim.x * blockDim.x) >> 6;
    for (int e = wave; e < n_edges; e += nw) {
        int s = src[e], d = dst[e], r = et[e];
        float v = h[(size_t)s * DIM + lane];
        unsafeAtomicAdd(&S[((size_t)d * NRELS + r) * DIM + lane], v);
    }
}

// Broadcast-row matmul: out[n][c] = bias[c] + sum_k X[n][k] * Wcat[k][c]
// X = [h | S] (576 cols when NKB==9; just h when NKB==1).
// One wave owns 32 rows; lane = output col. W k-block held in 64 VGPRs,
// x-values loaded as wave-uniform float4 (broadcast), acc statically indexed.
template <int NKB>
__global__ __launch_bounds__(256) void rgcn_matmul(const float* __restrict__ h,
                                                   const float* __restrict__ S,
                                                   const float* __restrict__ Wcat,
                                                   const float* __restrict__ bias,
                                                   float* __restrict__ out, int n_nodes) {
    const int lane = threadIdx.x & 63;
    const int wid = blockIdx.x * (blockDim.x >> 6) + (threadIdx.x >> 6);
    const int ngroups = (n_nodes + 31) >> 5;
    if (wid >= ngroups) return;
    const long n0 = (long)wid * 32;
    const long nmax = (long)n_nodes - 1;

    float acc[32];
    float bv = bias[lane];
#pragma unroll
    for (int r = 0; r < 32; ++r) acc[r] = bv;

    for (int kb = 0; kb < NKB; ++kb) {
        // Stage W k-block into registers: w[k] = Wcat[kb*64+k][lane]
        float w[64];
        const float* wp = Wcat + (size_t)kb * 64 * DIM + lane;
#pragma unroll
        for (int k = 0; k < 64; ++k) w[k] = wp[(size_t)k * DIM];

#pragma unroll
        for (int r = 0; r < 32; ++r) {
            long n = n0 + r;
            if (n > nmax) n = nmax;  // clamp (harmless recompute; store is exact-guarded)
            const float* xp = (kb == 0) ? (h + n * DIM)
                                        : (S + n * (NRELS * DIM) + (size_t)(kb - 1) * DIM);
            const float4* xq = (const float4*)xp;
#pragma unroll
            for (int q = 0; q < 16; ++q) {
                float4 x = xq[q];  // wave-uniform address -> single 16B broadcast load
                acc[r] += x.x * w[4 * q + 0];
                acc[r] += x.y * w[4 * q + 1];
                acc[r] += x.z * w[4 * q + 2];
                acc[r] += x.w * w[4 * q + 3];
            }
        }
    }
#pragma unroll
    for (int r = 0; r < 32; ++r) {
        long n = n0 + r;
        if (n < n_nodes) out[n * DIM + lane] = acc[r];
    }
}

// Fallback (small ws): per-edge matvec, atomics into out
__global__ void edge_matvec(const int* __restrict__ src, const int* __restrict__ dst,
                            const int* __restrict__ et, const float* __restrict__ h,
                            const float* __restrict__ Wcat, float* __restrict__ out,
                            int n_edges) {
    int gid = blockIdx.x * blockDim.x + threadIdx.x;
    int wave = gid >> 6, lane = gid & 63;
    int nw = (gridDim.x * blockDim.x) >> 6;
    for (int e = wave; e < n_edges; e += nw) {
        int s = src[e], d = dst[e], r = et[e];
        const float4* xq = (const float4*)(h + (size_t)s * DIM);
        float acc = 0.f;
#pragma unroll
        for (int q = 0; q < 16; ++q) {
            float4 x = xq[q];
            acc += x.x * Wcat[(DIM + r * DIM + 4 * q + 0) * DIM + lane];
            acc += x.y * Wcat[(DIM + r * DIM + 4 * q + 1) * DIM + lane];
            acc += x.z * Wcat[(DIM + r * DIM + 4 * q + 2) * DIM + lane];
            acc += x.w * Wcat[(DIM + r * DIM + 4 * q + 3) * DIM + lane];
        }
        unsafeAtomicAdd(&out[(size_t)d * DIM + lane], acc);
    }
}

extern "C" void kernel_launch(void* const* d_in, const int* in_sizes, int n_in,
                              void* d_out, int out_size, void* d_ws, size_t ws_size,
                              hipStream_t stream) {
    const int* src = (const int*)d_in[0];
    const int* dst = (const int*)d_in[1];
    const int* et  = (const int*)d_in[2];
    const float* emb    = (const float*)d_in[3];
    const float* bases1 = (const float*)d_in[4];
    const float* coef1  = (const float*)d_in[5];
    const float* wself1 = (const float*)d_in[6];
    const float* bias1  = (const float*)d_in[7];
    const float* bases2 = (const float*)d_in[8];
    const float* coef2  = (const float*)d_in[9];
    const float* wself2 = (const float*)d_in[10];
    const float* bias2  = (const float*)d_in[11];
    float* out = (float*)d_out;

    const int NE = in_sizes[0];
    const int NN = in_sizes[3] / DIM;

    float* Wcat1 = (float*)d_ws;
    float* Wcat2 = Wcat1 + KROWS * DIM;
    float* h1    = Wcat2 + KROWS * DIM;
    float* S     = h1 + (size_t)NN * DIM;

    size_t need_dense = ((size_t)2 * KROWS * DIM + (size_t)NN * DIM + (size_t)NN * NRELS * DIM) * 4;

    build_wcat<<<(KROWS * DIM + 255) / 256, 256, 0, stream>>>(bases1, coef1, wself1, Wcat1);
    build_wcat<<<(KROWS * DIM + 255) / 256, 256, 0, stream>>>(bases2, coef2, wself2, Wcat2);

    const int ngroups = (NN + 31) >> 5;
    const int mm_blocks = (ngroups + 3) / 4;  // 4 waves per 256-thread block

    if (ws_size >= need_dense) {
        size_t sbytes = (size_t)NN * NRELS * DIM * 4;
        hipMemsetAsync(S, 0, sbytes, stream);
        scatter_kernel<<<2048, 256, 0, stream>>>(src, dst, et, emb, S, NE);
        rgcn_matmul<9><<<mm_blocks, 256, 0, stream>>>(emb, S, Wcat1, bias1, h1, NN);
        hipMemsetAsync(S, 0, sbytes, stream);
        scatter_kernel<<<2048, 256, 0, stream>>>(src, dst, et, h1, S, NE);
        rgcn_matmul<9><<<mm_blocks, 256, 0, stream>>>(h1, S, Wcat2, bias2, out, NN);
    } else {
        rgcn_matmul<1><<<mm_blocks, 256, 0, stream>>>(emb, nullptr, Wcat1, bias1, h1, NN);
        edge_matvec<<<2048, 256, 0, stream>>>(src, dst, et, emb, Wcat1, h1, NE);
        rgcn_matmul<1><<<mm_blocks, 256, 0, stream>>>(h1, nullptr, Wcat2, bias2, out, NN);
        edge_matvec<<<2048, 256, 0, stream>>>(src, dst, et, h1, Wcat2, out, NE);
    }
}

// Round 3
// 596.820 us; speedup vs baseline: 7.5844x; 4.2057x over previous
//
#include <hip/hip_runtime.h>
#include <hip/hip_bf16.h>

#define DIM 64
#define NRELS 8
#define NBASES 4
#define NW 9  // 8 relations + self

typedef __attribute__((ext_vector_type(8))) short short8;
typedef __attribute__((ext_vector_type(4))) float f32x4;

__device__ inline unsigned short f2bf(float f) {
    union { float f; unsigned int u; } v; v.f = f;
    unsigned int u = v.u;
    unsigned int r = u + 0x7FFFu + ((u >> 16) & 1u);  // round-to-nearest-even
    return (unsigned short)(r >> 16);
}
__device__ inline float bf2f(unsigned short s) {
    union { unsigned int u; float f; } v; v.u = ((unsigned int)s) << 16;
    return v.f;
}

// Pack W matrices (8 relation + 1 self) into MFMA B-fragment order, bf16.
// B element for mfma_f32_16x16x32_bf16: k = half*32 + (lane>>4)*8 + e, j = jt*16 + (lane&15)
// Wpk flat index: (((r*4 + jt)*2 + half)*64 + lane)*8 + e
__global__ void build_wpk(const float* __restrict__ bases, const float* __restrict__ coef,
                          const float* __restrict__ wself, unsigned short* __restrict__ Wpk) {
    int idx = blockIdx.x * blockDim.x + threadIdx.x;
    if (idx >= NW * DIM * DIM) return;
    int r = idx >> 12;         // 0..8
    int k = (idx >> 6) & 63;   // input dim
    int j = idx & 63;          // output dim
    float v;
    if (r < NRELS) {
        v = 0.f;
#pragma unroll
        for (int b = 0; b < NBASES; ++b)
            v += coef[r * NBASES + b] * bases[((size_t)b * DIM + k) * DIM + j];
    } else {
        v = wself[k * DIM + j];
    }
    int half = k >> 5, e = k & 7, laneHi = (k >> 3) & 3;
    int jt = j >> 4, laneLo = j & 15;
    int lane = laneHi * 16 + laneLo;
    Wpk[(size_t)((((r * 4 + jt) * 2 + half) * 64 + lane) * 8 + e)] = f2bf(v);
}

// Per 64-node block tile (4 waves x 16 nodes):
//   hproj[r][n][:] = bf16( h[n] @ W_r )    for r = 0..7
//   outself[n][:]  = h[n] @ wself + bias   (f32)
__global__ __launch_bounds__(256) void proj_kernel(const float* __restrict__ h,
                                                   const unsigned short* __restrict__ Wpk,
                                                   const float* __restrict__ bias,
                                                   unsigned short* __restrict__ hproj,
                                                   float* __restrict__ outself, int n_nodes) {
    const int lane = threadIdx.x & 63;
    const int wave = threadIdx.x >> 6;
    const int n0 = blockIdx.x * 64 + wave * 16;
    if (n0 >= n_nodes) return;
    const int lrow = lane & 15;  // A row within tile / D col
    const int lhi = lane >> 4;   // k-group / D row-group

    int row = n0 + lrow;
    if (row >= n_nodes) row = n_nodes - 1;  // clamp loads; stores are guarded
    const float* hrow = h + (size_t)row * DIM + lhi * 8;
    float4 x0 = *(const float4*)(hrow);
    float4 x1 = *(const float4*)(hrow + 4);
    float4 x2 = *(const float4*)(hrow + 32);
    float4 x3 = *(const float4*)(hrow + 36);
    short8 a0, a1;
    a0[0] = (short)f2bf(x0.x); a0[1] = (short)f2bf(x0.y);
    a0[2] = (short)f2bf(x0.z); a0[3] = (short)f2bf(x0.w);
    a0[4] = (short)f2bf(x1.x); a0[5] = (short)f2bf(x1.y);
    a0[6] = (short)f2bf(x1.z); a0[7] = (short)f2bf(x1.w);
    a1[0] = (short)f2bf(x2.x); a1[1] = (short)f2bf(x2.y);
    a1[2] = (short)f2bf(x2.z); a1[3] = (short)f2bf(x2.w);
    a1[4] = (short)f2bf(x3.x); a1[5] = (short)f2bf(x3.y);
    a1[6] = (short)f2bf(x3.z); a1[7] = (short)f2bf(x3.w);

    for (int r = 0; r < NW; ++r) {
#pragma unroll
        for (int jt = 0; jt < 4; ++jt) {
            const unsigned short* bbase = Wpk + (size_t)(((r * 4 + jt) * 2) * 64 + lane) * 8;
            short8 b0 = *(const short8*)bbase;
            short8 b1 = *(const short8*)(bbase + 512);
            f32x4 c = {0.f, 0.f, 0.f, 0.f};
            c = __builtin_amdgcn_mfma_f32_16x16x32_bf16(a0, b0, c, 0, 0, 0);
            c = __builtin_amdgcn_mfma_f32_16x16x32_bf16(a1, b1, c, 0, 0, 0);
            int j = jt * 16 + lrow;
            if (r < NRELS) {
                unsigned short* hp = hproj + ((size_t)r * n_nodes + n0) * DIM + j;
#pragma unroll
                for (int reg = 0; reg < 4; ++reg) {
                    int i = lhi * 4 + reg;
                    if (n0 + i < n_nodes) hp[(size_t)i * DIM] = f2bf(c[reg]);
                }
            } else {
                float bj = bias[j];
                float* op = outself + (size_t)n0 * DIM + j;
#pragma unroll
                for (int reg = 0; reg < 4; ++reg) {
                    int i = lhi * 4 + reg;
                    if (n0 + i < n_nodes) op[(size_t)i * DIM] = c[reg] + bj;
                }
            }
        }
    }
}

// out[dst][c] += hproj[etype][src][c]  — lane = c, one edge per wave-iteration
__global__ void scatter_kernel(const int* __restrict__ src, const int* __restrict__ dst,
                               const int* __restrict__ et,
                               const unsigned short* __restrict__ hproj,
                               float* __restrict__ out, int n_edges, int n_nodes) {
    int gid = blockIdx.x * blockDim.x + threadIdx.x;
    int wid = gid >> 6, lane = gid & 63;
    int nw = (gridDim.x * blockDim.x) >> 6;
    for (int e = wid; e < n_edges; e += nw) {
        int s = src[e], d = dst[e], r = et[e];
        float v = bf2f(hproj[((size_t)r * n_nodes + s) * DIM + lane]);
        unsafeAtomicAdd(&out[(size_t)d * DIM + lane], v);
    }
}

extern "C" void kernel_launch(void* const* d_in, const int* in_sizes, int n_in,
                              void* d_out, int out_size, void* d_ws, size_t ws_size,
                              hipStream_t stream) {
    const int* src = (const int*)d_in[0];
    const int* dst = (const int*)d_in[1];
    const int* et  = (const int*)d_in[2];
    const float* emb    = (const float*)d_in[3];
    const float* bases1 = (const float*)d_in[4];
    const float* coef1  = (const float*)d_in[5];
    const float* wself1 = (const float*)d_in[6];
    const float* bias1  = (const float*)d_in[7];
    const float* bases2 = (const float*)d_in[8];
    const float* coef2  = (const float*)d_in[9];
    const float* wself2 = (const float*)d_in[10];
    const float* bias2  = (const float*)d_in[11];
    float* out = (float*)d_out;

    const int NE = in_sizes[0];
    const int NN = in_sizes[3] / DIM;

    // Workspace layout (bytes): Wpk1 | Wpk2 | h1 | hproj   (~128.2 MB; round-1 proved ws >= 231 MB)
    unsigned short* Wpk1 = (unsigned short*)d_ws;
    unsigned short* Wpk2 = Wpk1 + (size_t)NW * DIM * DIM;
    float* h1 = (float*)(Wpk2 + (size_t)NW * DIM * DIM);
    unsigned short* hproj = (unsigned short*)(h1 + (size_t)NN * DIM);

    const int wpk_threads = NW * DIM * DIM;
    build_wpk<<<(wpk_threads + 255) / 256, 256, 0, stream>>>(bases1, coef1, wself1, Wpk1);
    build_wpk<<<(wpk_threads + 255) / 256, 256, 0, stream>>>(bases2, coef2, wself2, Wpk2);

    const int proj_blocks = (NN + 63) / 64;

    // Layer 1: h1 = emb @ wself1 + bias1; hproj = emb @ W_r; h1 += scatter
    proj_kernel<<<proj_blocks, 256, 0, stream>>>(emb, Wpk1, bias1, hproj, h1, NN);
    scatter_kernel<<<2048, 256, 0, stream>>>(src, dst, et, hproj, h1, NE, NN);

    // Layer 2: out = h1 @ wself2 + bias2; hproj = h1 @ W_r; out += scatter
    proj_kernel<<<proj_blocks, 256, 0, stream>>>(h1, Wpk2, bias2, hproj, out, NN);
    scatter_kernel<<<2048, 256, 0, stream>>>(src, dst, et, hproj, out, NE, NN);
}

// Round 4
// 335.441 us; speedup vs baseline: 13.4942x; 1.7792x over previous
//
#include <hip/hip_runtime.h>
#include <hip/hip_bf16.h>

#define DIM 64
#define NRELS 8
#define NBASES 4
#define NW 9            // 8 relations + self
#define SCAN_CHUNK 2048 // 256 threads * 8 elems

typedef __attribute__((ext_vector_type(8))) short short8;
typedef __attribute__((ext_vector_type(4))) float f32x4;

__device__ inline unsigned short f2bf(float f) {
    union { float f; unsigned int u; } v; v.f = f;
    unsigned int u = v.u;
    unsigned int r = u + 0x7FFFu + ((u >> 16) & 1u);  // round-to-nearest-even
    return (unsigned short)(r >> 16);
}
__device__ inline float bf2f(unsigned short s) {
    union { unsigned int u; float f; } v; v.u = ((unsigned int)s) << 16;
    return v.f;
}

// Pack W matrices (8 relation + 1 self) into MFMA B-fragment order, bf16.
// B element for mfma_f32_16x16x32_bf16: k = half*32 + (lane>>4)*8 + e, j = jt*16 + (lane&15)
__global__ void build_wpk(const float* __restrict__ bases, const float* __restrict__ coef,
                          const float* __restrict__ wself, unsigned short* __restrict__ Wpk) {
    int idx = blockIdx.x * blockDim.x + threadIdx.x;
    if (idx >= NW * DIM * DIM) return;
    int r = idx >> 12;         // 0..8
    int k = (idx >> 6) & 63;   // input dim
    int j = idx & 63;          // output dim
    float v;
    if (r < NRELS) {
        v = 0.f;
#pragma unroll
        for (int b = 0; b < NBASES; ++b)
            v += coef[r * NBASES + b] * bases[((size_t)b * DIM + k) * DIM + j];
    } else {
        v = wself[k * DIM + j];
    }
    int half = k >> 5, e = k & 7, laneHi = (k >> 3) & 3;
    int jt = j >> 4, laneLo = j & 15;
    int lane = laneHi * 16 + laneLo;
    Wpk[(size_t)((((r * 4 + jt) * 2 + half) * 64 + lane) * 8 + e)] = f2bf(v);
}

// Per 64-node tile (4 waves x 16 nodes):
//   hproj[r][n][:] = bf16( h[n] @ W_r ),  outself[n][:] = h[n] @ wself + bias (f32)
__global__ __launch_bounds__(256) void proj_kernel(const float* __restrict__ h,
                                                   const unsigned short* __restrict__ Wpk,
                                                   const float* __restrict__ bias,
                                                   unsigned short* __restrict__ hproj,
                                                   float* __restrict__ outself, int n_nodes) {
    const int lane = threadIdx.x & 63;
    const int wave = threadIdx.x >> 6;
    const int n0 = blockIdx.x * 64 + wave * 16;
    if (n0 >= n_nodes) return;
    const int lrow = lane & 15;
    const int lhi = lane >> 4;

    int row = n0 + lrow;
    if (row >= n_nodes) row = n_nodes - 1;
    const float* hrow = h + (size_t)row * DIM + lhi * 8;
    float4 x0 = *(const float4*)(hrow);
    float4 x1 = *(const float4*)(hrow + 4);
    float4 x2 = *(const float4*)(hrow + 32);
    float4 x3 = *(const float4*)(hrow + 36);
    short8 a0, a1;
    a0[0] = (short)f2bf(x0.x); a0[1] = (short)f2bf(x0.y);
    a0[2] = (short)f2bf(x0.z); a0[3] = (short)f2bf(x0.w);
    a0[4] = (short)f2bf(x1.x); a0[5] = (short)f2bf(x1.y);
    a0[6] = (short)f2bf(x1.z); a0[7] = (short)f2bf(x1.w);
    a1[0] = (short)f2bf(x2.x); a1[1] = (short)f2bf(x2.y);
    a1[2] = (short)f2bf(x2.z); a1[3] = (short)f2bf(x2.w);
    a1[4] = (short)f2bf(x3.x); a1[5] = (short)f2bf(x3.y);
    a1[6] = (short)f2bf(x3.z); a1[7] = (short)f2bf(x3.w);

    for (int r = 0; r < NW; ++r) {
#pragma unroll
        for (int jt = 0; jt < 4; ++jt) {
            const unsigned short* bbase = Wpk + (size_t)(((r * 4 + jt) * 2) * 64 + lane) * 8;
            short8 b0 = *(const short8*)bbase;
            short8 b1 = *(const short8*)(bbase + 512);
            f32x4 c = {0.f, 0.f, 0.f, 0.f};
            c = __builtin_amdgcn_mfma_f32_16x16x32_bf16(a0, b0, c, 0, 0, 0);
            c = __builtin_amdgcn_mfma_f32_16x16x32_bf16(a1, b1, c, 0, 0, 0);
            int j = jt * 16 + lrow;
            if (r < NRELS) {
                unsigned short* hp = hproj + ((size_t)r * n_nodes + n0) * DIM + j;
#pragma unroll
                for (int reg = 0; reg < 4; ++reg) {
                    int i = lhi * 4 + reg;
                    if (n0 + i < n_nodes) hp[(size_t)i * DIM] = f2bf(c[reg]);
                }
            } else {
                float bj = bias[j];
                float* op = outself + (size_t)n0 * DIM + j;
#pragma unroll
                for (int reg = 0; reg < 4; ++reg) {
                    int i = lhi * 4 + reg;
                    if (n0 + i < n_nodes) op[(size_t)i * DIM] = c[reg] + bj;
                }
            }
        }
    }
}

// ---- CSR build (once; reused by both layers) ----
__global__ void hist_kernel(const int* __restrict__ dst, int* __restrict__ deg, int n_edges) {
    int e = blockIdx.x * blockDim.x + threadIdx.x;
    if (e < n_edges) atomicAdd(&deg[dst[e]], 1);
}

__global__ __launch_bounds__(256) void scan1(const int* __restrict__ deg, int* __restrict__ off,
                                             int* __restrict__ bsum, int n) {
    int t = threadIdx.x, b = blockIdx.x;
    int lane = t & 63, w = t >> 6;
    int base = b * SCAN_CHUNK + t * 8;
    int v[8]; int s = 0;
#pragma unroll
    for (int k = 0; k < 8; ++k) { int x = (base + k < n) ? deg[base + k] : 0; v[k] = x; s += x; }
    int x = s;
#pragma unroll
    for (int ofs = 1; ofs < 64; ofs <<= 1) {
        int y = __shfl_up(x, ofs);
        if (lane >= ofs) x += y;
    }
    __shared__ int wtot[4];
    if (lane == 63) wtot[w] = x;
    __syncthreads();
    int woff = 0;
    for (int k = 0; k < w; ++k) woff += wtot[k];
    int run = woff + x - s;  // exclusive prefix for this thread's 8 elems
#pragma unroll
    for (int k = 0; k < 8; ++k) { if (base + k < n) off[base + k] = run; run += v[k]; }
    if (t == 255) bsum[b] = woff + x;  // block total
}

__global__ void scan2(int* __restrict__ bsum, int nb) {
    if (nb <= 64) {
        int lane = threadIdx.x & 63;
        int v = (lane < nb) ? bsum[lane] : 0;
        int x = v;
#pragma unroll
        for (int ofs = 1; ofs < 64; ofs <<= 1) {
            int y = __shfl_up(x, ofs);
            if ((threadIdx.x & 63) >= ofs) x += y;
        }
        if (lane < nb) bsum[lane] = x - v;  // exclusive
    } else if (threadIdx.x == 0 && blockIdx.x == 0) {
        int run = 0;
        for (int b = 0; b < nb; ++b) { int v = bsum[b]; bsum[b] = run; run += v; }
    }
}

__global__ void scan3(const int* __restrict__ bsum, int* __restrict__ off,
                      int* __restrict__ pos, int n) {
    int i = blockIdx.x * blockDim.x + threadIdx.x;
    if (i < n) { int v = off[i] + bsum[i / SCAN_CHUNK]; off[i] = v; pos[i] = v; }
}

__global__ void reorder_kernel(const int* __restrict__ src, const int* __restrict__ dst,
                               const int* __restrict__ et, int* __restrict__ pos,
                               unsigned* __restrict__ perm, int n_edges) {
    int e = blockIdx.x * blockDim.x + threadIdx.x;
    if (e < n_edges) {
        int p = atomicAdd(&pos[dst[e]], 1);
        perm[p] = (unsigned)src[e] | ((unsigned)et[e] << 20);
    }
}
// After reorder: pos[d] == off[d] + deg[d] == segment end.

// One wave per dst: out[d] += sum over its edges of hproj[et][src]
__global__ __launch_bounds__(256) void gather_kernel(const unsigned* __restrict__ perm,
                                                     const int* __restrict__ off,
                                                     const int* __restrict__ pos,
                                                     const unsigned short* __restrict__ hproj,
                                                     float* __restrict__ out, int n_nodes) {
    int gid = blockIdx.x * blockDim.x + threadIdx.x;
    int d = gid >> 6, lane = gid & 63;
    if (d >= n_nodes) return;
    int beg = off[d], end = pos[d];
    float acc = out[(size_t)d * DIM + lane];
    int i = beg;
    for (; i + 4 <= end; i += 4) {
        unsigned u0 = perm[i], u1 = perm[i + 1], u2 = perm[i + 2], u3 = perm[i + 3];
        float v0 = bf2f(hproj[((size_t)(u0 >> 20) * n_nodes + (u0 & 0xFFFFFu)) * DIM + lane]);
        float v1 = bf2f(hproj[((size_t)(u1 >> 20) * n_nodes + (u1 & 0xFFFFFu)) * DIM + lane]);
        float v2 = bf2f(hproj[((size_t)(u2 >> 20) * n_nodes + (u2 & 0xFFFFFu)) * DIM + lane]);
        float v3 = bf2f(hproj[((size_t)(u3 >> 20) * n_nodes + (u3 & 0xFFFFFu)) * DIM + lane]);
        acc += v0; acc += v1; acc += v2; acc += v3;
    }
    for (; i < end; ++i) {
        unsigned u = perm[i];
        acc += bf2f(hproj[((size_t)(u >> 20) * n_nodes + (u & 0xFFFFFu)) * DIM + lane]);
    }
    out[(size_t)d * DIM + lane] = acc;
}

extern "C" void kernel_launch(void* const* d_in, const int* in_sizes, int n_in,
                              void* d_out, int out_size, void* d_ws, size_t ws_size,
                              hipStream_t stream) {
    const int* src = (const int*)d_in[0];
    const int* dst = (const int*)d_in[1];
    const int* et  = (const int*)d_in[2];
    const float* emb    = (const float*)d_in[3];
    const float* bases1 = (const float*)d_in[4];
    const float* coef1  = (const float*)d_in[5];
    const float* wself1 = (const float*)d_in[6];
    const float* bias1  = (const float*)d_in[7];
    const float* bases2 = (const float*)d_in[8];
    const float* coef2  = (const float*)d_in[9];
    const float* wself2 = (const float*)d_in[10];
    const float* bias2  = (const float*)d_in[11];
    float* out = (float*)d_out;

    const int NE = in_sizes[0];
    const int NN = in_sizes[3] / DIM;
    const int NB = (NN + SCAN_CHUNK - 1) / SCAN_CHUNK;

    // Workspace layout (~134 MB; ws proved >= 231 MB in round 1)
    unsigned short* Wpk1 = (unsigned short*)d_ws;
    unsigned short* Wpk2 = Wpk1 + (size_t)NW * DIM * DIM;
    float* h1 = (float*)(Wpk2 + (size_t)NW * DIM * DIM);
    unsigned short* hproj = (unsigned short*)(h1 + (size_t)NN * DIM);
    int* deg  = (int*)(hproj + (size_t)NRELS * NN * DIM);
    int* off  = deg + NN;
    int* pos  = off + NN;
    int* bsum = pos + NN;
    unsigned* perm = (unsigned*)(bsum + ((NB + 63) & ~63));

    const int wpk_threads = NW * DIM * DIM;
    build_wpk<<<(wpk_threads + 255) / 256, 256, 0, stream>>>(bases1, coef1, wself1, Wpk1);
    build_wpk<<<(wpk_threads + 255) / 256, 256, 0, stream>>>(bases2, coef2, wself2, Wpk2);

    // CSR build (once, reused by both layers)
    hipMemsetAsync(deg, 0, (size_t)NN * 4, stream);
    hist_kernel<<<(NE + 255) / 256, 256, 0, stream>>>(dst, deg, NE);
    scan1<<<NB, 256, 0, stream>>>(deg, off, bsum, NN);
    scan2<<<1, 64, 0, stream>>>(bsum, NB);
    scan3<<<(NN + 255) / 256, 256, 0, stream>>>(bsum, off, pos, NN);
    reorder_kernel<<<(NE + 255) / 256, 256, 0, stream>>>(src, dst, et, pos, perm, NE);

    const int proj_blocks = (NN + 63) / 64;
    const int gath_blocks = (NN + 3) / 4;  // one wave per dst node

    // Layer 1
    proj_kernel<<<proj_blocks, 256, 0, stream>>>(emb, Wpk1, bias1, hproj, h1, NN);
    gather_kernel<<<gath_blocks, 256, 0, stream>>>(perm, off, pos, hproj, h1, NN);

    // Layer 2
    proj_kernel<<<proj_blocks, 256, 0, stream>>>(h1, Wpk2, bias2, hproj, out, NN);
    gather_kernel<<<gath_blocks, 256, 0, stream>>>(perm, off, pos, hproj, out, NN);
}